// Round 4
// baseline (226.333 us; speedup 1.0000x reference)
//
#include <hip/hip_runtime.h>

#define B_ 2
#define T_ 2048
#define C_ 1024
#define H_ 16
#define D_ 64
#define M_ (B_ * T_)       // 4096 rows
#define NQKV_ (3 * C_)     // 3072

typedef unsigned short us16;
typedef short bf16x8 __attribute__((ext_vector_type(8)));
typedef float f32x4 __attribute__((ext_vector_type(4)));

__device__ __forceinline__ f32x4 mfma16(bf16x8 a, bf16x8 b, f32x4 c) {
    return __builtin_amdgcn_mfma_f32_16x16x32_bf16(a, b, c, 0, 0, 0);
}

// float -> bf16 with round-to-nearest-even
__device__ __forceinline__ us16 f2bf(float f) {
    union { float f; unsigned int u; } v; v.f = f;
    unsigned int r = v.u + 0x7fffu + ((v.u >> 16) & 1u);
    return (us16)(r >> 16);
}

// two floats -> packed bf16 pair (single VALU op)
__device__ __forceinline__ unsigned int cvt_pk_bf16(float lo, float hi) {
    unsigned int r;
    asm("v_cvt_pk_bf16_f32 %0, %1, %2" : "=v"(r) : "v"(lo), "v"(hi));
    return r;
}

// async global->LDS, 16 B per lane; ldst must be wave-uniform (HW adds lane*16)
__device__ __forceinline__ void gl_lds16(const us16* g, us16* l) {
    __builtin_amdgcn_global_load_lds(
        (const __attribute__((address_space(1))) void*)g,
        (__attribute__((address_space(3))) void*)l,
        16, 0, 0);
}

// ---------------------------------------------------------------------------
// fp32 -> bf16 convert (8 elems/thread)
// ---------------------------------------------------------------------------
__global__ __launch_bounds__(256) void cvt_bf16(
    const float* __restrict__ in, us16* __restrict__ out, int n8)
{
    const int i = blockIdx.x * blockDim.x + threadIdx.x;
    if (i >= n8) return;
    const float4 a = ((const float4*)in)[2 * i];
    const float4 b = ((const float4*)in)[2 * i + 1];
    ushort4 lo = { f2bf(a.x), f2bf(a.y), f2bf(a.z), f2bf(a.w) };
    ushort4 hi = { f2bf(b.x), f2bf(b.y), f2bf(b.z), f2bf(b.w) };
    ((ushort4*)out)[2 * i] = lo;
    ((ushort4*)out)[2 * i + 1] = hi;
}

// ---------------------------------------------------------------------------
// W [K][N] fp32  ->  Wt [N][K] bf16   (32x32 LDS tiles)
// ---------------------------------------------------------------------------
__global__ __launch_bounds__(256) void transpose_cvt(
    const float* __restrict__ W, us16* __restrict__ Wt, int K, int N)
{
    __shared__ float tile[32][33];
    const int n0 = blockIdx.x * 32, k0 = blockIdx.y * 32;
    const int t = threadIdx.x;
    {
        const int k = t >> 3, n4 = (t & 7) * 4;
        const float4 v = *(const float4*)(W + (size_t)(k0 + k) * N + n0 + n4);
        tile[k][n4 + 0] = v.x; tile[k][n4 + 1] = v.y;
        tile[k][n4 + 2] = v.z; tile[k][n4 + 3] = v.w;
    }
    __syncthreads();
    {
        const int n = t >> 3, k4 = (t & 7) * 4;
        ushort4 o = { f2bf(tile[k4 + 0][n]), f2bf(tile[k4 + 1][n]),
                      f2bf(tile[k4 + 2][n]), f2bf(tile[k4 + 3][n]) };
        *(ushort4*)(Wt + (size_t)(n0 + n) * K + k0 + k4) = o;
    }
}

// ---------------------------------------------------------------------------
// bf16 MFMA GEMM: C[M][N] = A[M][K] @ Bt[N][K]^T + bias
// 128x128 block tile, BK=64, 4 waves each computing 64x64 (4x4 MFMA tiles).
// Staging via global_load_lds width=16 (async, no VGPR round-trip): LDS is
// LINEAR [128][64] (wave-uniform dest + lane*16B; padding forbidden, m104).
// The 16-way ds_read bank conflict this creates is off the critical path at
// this 2-phase structure (m233/m97: 874 TF with exactly this layout).
// out_bf16: write bf16 via LDS-packed coalesced stores, else fp32 scalar.
// ---------------------------------------------------------------------------
__global__ __launch_bounds__(256) void gemm_bf16(
    const us16* __restrict__ A, const us16* __restrict__ Bt,
    const float* __restrict__ bias, void* __restrict__ Cout,
    int M, int N, int K, int out_bf16)
{
    // staging needs 2*128*64 = 16384 elems; epilogue Cs needs 128*136 = 17408
    __shared__ __align__(16) us16 smem[128 * 136];
    us16* sA = smem;                  // [128][64] linear
    us16* sB = smem + 128 * 64;       // [128][64] linear

    const int tid = threadIdx.x;
    const int lane = tid & 63, wave = tid >> 6;
    const int wr = wave >> 1, wc = wave & 1;
    const int cq = lane & 15, quad = lane >> 4;
    const int m0 = blockIdx.y * 128, n0 = blockIdx.x * 128;

    const int srow = lane >> 3;          // row within 8-row wave chunk
    const int scol = (lane & 7) * 8;     // elem col (16B granules)

    f32x4 acc[4][4];
    #pragma unroll
    for (int i = 0; i < 4; ++i)
        #pragma unroll
        for (int j = 0; j < 4; ++j)
            acc[i][j] = (f32x4){0.f, 0.f, 0.f, 0.f};

    for (int k0 = 0; k0 < K; k0 += 64) {
        // ---- async stage: 4 chunks x (A,B); dest wave-uniform, src per-lane
        #pragma unroll
        for (int p = 0; p < 4; ++p) {
            const int r = p * 32 + wave * 8;     // wave-chunk base row
            gl_lds16(A  + (size_t)(m0 + r + srow) * K + k0 + scol, sA + r * 64);
            gl_lds16(Bt + (size_t)(n0 + r + srow) * K + k0 + scol, sB + r * 64);
        }
        __syncthreads();   // drains vmcnt -> tiles resident

        #pragma unroll
        for (int kk = 0; kk < 64; kk += 32) {
            const int ko = kk + quad * 8;
            bf16x8 af[4], bfg[4];
            #pragma unroll
            for (int i = 0; i < 4; ++i) {
                af[i]  = *(const bf16x8*)(sA + (wr * 64 + i * 16 + cq) * 64 + ko);
                bfg[i] = *(const bf16x8*)(sB + (wc * 64 + i * 16 + cq) * 64 + ko);
            }
            #pragma unroll
            for (int mi = 0; mi < 4; ++mi)
                #pragma unroll
                for (int ni = 0; ni < 4; ++ni)
                    acc[mi][ni] = mfma16(af[mi], bfg[ni], acc[mi][ni]);
        }
        __syncthreads();
    }

    // ---- epilogue ----
    if (out_bf16) {
        us16* Cs = smem;   // 128 x 136 (pad keeps 16B row alignment)
        #pragma unroll
        for (int mi = 0; mi < 4; ++mi)
            #pragma unroll
            for (int ni = 0; ni < 4; ++ni) {
                const int n = n0 + wc * 64 + ni * 16 + cq;
                const float bv = bias[n];
                #pragma unroll
                for (int r = 0; r < 4; ++r)
                    Cs[(wr * 64 + mi * 16 + quad * 4 + r) * 136 +
                       wc * 64 + ni * 16 + cq] = f2bf(acc[mi][ni][r] + bv);
            }
        __syncthreads();
        us16* Co = (us16*)Cout;
        #pragma unroll
        for (int p = 0; p < 8; ++p) {
            const int chunk = p * 256 + tid;
            const int r = chunk >> 4, c = (chunk & 15) * 8;
            *(uint4*)(Co + (size_t)(m0 + r) * N + n0 + c) =
                *(const uint4*)(Cs + r * 136 + c);
        }
    } else {
        float* Co = (float*)Cout;
        #pragma unroll
        for (int mi = 0; mi < 4; ++mi)
            #pragma unroll
            for (int ni = 0; ni < 4; ++ni) {
                const int n = n0 + wc * 64 + ni * 16 + cq;
                const float bv = bias[n];
                #pragma unroll
                for (int r = 0; r < 4; ++r)
                    Co[(size_t)(m0 + wr * 64 + mi * 16 + quad * 4 + r) * N + n] =
                        acc[mi][ni][r] + bv;
            }
    }
}

// ---------------------------------------------------------------------------
// MFMA flash attention (bf16 inputs, fp32 accum, causal).
// R1 VERBATIM (known-good at 71.4 us): fixed-shift softmax, ones-MFMA row
// sums, O^T PV, plain Ps layout, direct global->LDS staging, no setprio.
// The R2/R3 T14 reg-staging restructure failed correctness twice and is
// reverted wholesale pending a root-cause.
// ---------------------------------------------------------------------------
__global__ __launch_bounds__(256) void attn_mfma(
    const us16* __restrict__ qkv, us16* __restrict__ y)
{
    __shared__ __align__(16) us16 Ks[64][72];   // K tile, [t][d]
    __shared__ __align__(16) us16 Vt[64][72];   // V^T tile, [d][t]
    __shared__ __align__(16) us16 Ps[64][72];   // P, [q][t] (wave-private rows)

    const int tid = threadIdx.x;
    const int lane = tid & 63, wave = tid >> 6;
    const int cq = lane & 15, quad = lane >> 4;
    const int bh = blockIdx.x;
    const int qt = (int)gridDim.y - 1 - (int)blockIdx.y;   // heaviest first
    const int b = bh >> 4, h = bh & 15;

    const us16* base = qkv + (size_t)b * T_ * NQKV_ + h * D_;

    // Q fragments (A operand) straight from global; rows qt*64 + wave*16 + cq
    bf16x8 qf[2];
    {
        const us16* qrow = base + (size_t)(qt * 64 + wave * 16 + cq) * NQKV_;
        qf[0] = *(const bf16x8*)(qrow + quad * 8);
        qf[1] = *(const bf16x8*)(qrow + 32 + quad * 8);
    }

    // O^T accumulators: ot[dt][r] = O[d = dt*16+quad*4+r][q = wave*16+cq]
    f32x4 ot[4];
    #pragma unroll
    for (int j = 0; j < 4; ++j) ot[j] = (f32x4){0.f, 0.f, 0.f, 0.f};
    // row-sum accumulator: os[r] = sum_k P[q = wave*16+cq][k]  (all r equal)
    f32x4 os = (f32x4){0.f, 0.f, 0.f, 0.f};

    const bf16x8 onesf = (bf16x8){16256, 16256, 16256, 16256,
                                  16256, 16256, 16256, 16256}; // bf16 1.0 x8

    const float SCL = 0.125f * 1.44269504089f;   // fold 1/sqrt(D) and log2(e)
    const float SH  = -3.0f * 1.44269504089f;    // fixed shift (scores < 3)

    const int t2 = tid & 31, dc = tid >> 5;

    for (int kt = 0; kt <= qt; ++kt) {
        __syncthreads();   // previous iteration's MFMA reads complete
        // ---- stage K [t][d] ----
        #pragma unroll
        for (int p = 0; p < 2; ++p) {
            const int chunk = p * 256 + tid;
            const int r = chunk >> 3, c8 = (chunk & 7) * 8;
            const uint4 v = *(const uint4*)(base + (size_t)(kt * 64 + r) * NQKV_ + C_ + c8);
            *(uint4*)(&Ks[r][c8]) = v;
        }
        // ---- stage V transposed: Vt[d][t], packed pair writes ----
        {
            const us16* vp = base + (size_t)(kt * 64 + 2 * t2) * NQKV_ + 2 * C_ + dc * 8;
            const uint4 u0 = *(const uint4*)vp;
            const uint4 u1 = *(const uint4*)(vp + NQKV_);
            const us16* p0 = (const us16*)&u0;
            const us16* p1 = (const us16*)&u1;
            #pragma unroll
            for (int j = 0; j < 8; ++j) {
                const unsigned int packed =
                    (unsigned int)p0[j] | ((unsigned int)p1[j] << 16);
                *(unsigned int*)(&Vt[dc * 8 + j][2 * t2]) = packed;
            }
        }
        __syncthreads();

        // ---- S = Q K^T : 4 col tiles x (K=64 -> 2 mfma) ----
        f32x4 s[4];
        #pragma unroll
        for (int j = 0; j < 4; ++j) {
            const bf16x8 kf0 = *(const bf16x8*)(&Ks[j * 16 + cq][quad * 8]);
            const bf16x8 kf1 = *(const bf16x8*)(&Ks[j * 16 + cq][32 + quad * 8]);
            f32x4 t = (f32x4){0.f, 0.f, 0.f, 0.f};
            t = mfma16(qf[0], kf0, t);
            t = mfma16(qf[1], kf1, t);
            s[j] = t;
        }

        // ---- P = exp2(s*SCL + SH), causal mask on the diagonal tile ----
        float p[4][4];
        if (kt == qt) {
            const int qloc = wave * 16 + quad * 4;
            #pragma unroll
            for (int j = 0; j < 4; ++j) {
                const int kloc = j * 16 + cq;
                #pragma unroll
                for (int r = 0; r < 4; ++r) {
                    const float e = exp2f(fmaf(s[j][r], SCL, SH));
                    p[j][r] = (kloc > qloc + r) ? 0.f : e;
                }
            }
        } else {
            #pragma unroll
            for (int j = 0; j < 4; ++j)
                #pragma unroll
                for (int r = 0; r < 4; ++r)
                    p[j][r] = exp2f(fmaf(s[j][r], SCL, SH));
        }

        // ---- P -> LDS (wave-private rows; packed bf16 converts) ----
        #pragma unroll
        for (int j = 0; j < 4; ++j) {
            const unsigned int pk01 = cvt_pk_bf16(p[j][0], p[j][1]);
            const unsigned int pk23 = cvt_pk_bf16(p[j][2], p[j][3]);
            us16* pp = &Ps[wave * 16 + quad * 4][j * 16 + cq];
            pp[0]       = (us16)pk01;
            pp[72]      = (us16)(pk01 >> 16);
            pp[2 * 72]  = (us16)pk23;
            pp[3 * 72]  = (us16)(pk23 >> 16);
        }

        // ---- read P fragments back ----
        const bf16x8 pf0 = *(const bf16x8*)(&Ps[wave * 16 + cq][quad * 8]);
        const bf16x8 pf1 = *(const bf16x8*)(&Ps[wave * 16 + cq][32 + quad * 8]);

        // ---- O^T += V^T @ P^T ; row sums via ones-MFMA ----
        os = mfma16(onesf, pf0, os);
        os = mfma16(onesf, pf1, os);
        #pragma unroll
        for (int dt = 0; dt < 4; ++dt) {
            const bf16x8 vf0 = *(const bf16x8*)(&Vt[dt * 16 + cq][quad * 8]);
            const bf16x8 vf1 = *(const bf16x8*)(&Vt[dt * 16 + cq][32 + quad * 8]);
            ot[dt] = mfma16(vf0, pf0, ot[dt]);
            ot[dt] = mfma16(vf1, pf1, ot[dt]);
        }
    }

    // ---- epilogue: normalize, packed bf16 stores ----
    const float inv = 1.0f / os[0];
    const int row = qt * 64 + wave * 16 + cq;
    us16* yp = y + (size_t)(b * T_ + row) * C_ + h * D_ + quad * 4;
    #pragma unroll
    for (int dt = 0; dt < 4; ++dt) {
        ushort4 ov = { f2bf(ot[dt][0] * inv), f2bf(ot[dt][1] * inv),
                       f2bf(ot[dt][2] * inv), f2bf(ot[dt][3] * inv) };
        *(ushort4*)(yp + dt * 16) = ov;
    }
}

// ---------------------------------------------------------------------------
extern "C" void kernel_launch(void* const* d_in, const int* in_sizes, int n_in,
                              void* d_out, int out_size, void* d_ws, size_t ws_size,
                              hipStream_t stream)
{
    const float* x  = (const float*)d_in[0];   // [B,T,C]
    const float* aw = (const float*)d_in[1];   // [C,3C]
    const float* ab = (const float*)d_in[2];   // [3C]
    const float* pw = (const float*)d_in[3];   // [C,C]
    const float* pb = (const float*)d_in[4];   // [C]
    float* out = (float*)d_out;                // [B,T,C] fp32

    us16* xb   = (us16*)d_ws;                        // [4096][1024]
    us16* awT  = xb  + (size_t)M_ * C_;              // [3072][1024]
    us16* pwT  = awT + (size_t)NQKV_ * C_;           // [1024][1024]
    us16* qkvb = pwT + (size_t)C_ * C_;              // [4096][3072]
    us16* yb   = qkvb + (size_t)M_ * NQKV_;          // [4096][1024]

    // pre-pass: bf16 conversions
    cvt_bf16<<<(M_ * C_ / 8 + 255) / 256, 256, 0, stream>>>(x, xb, M_ * C_ / 8);
    transpose_cvt<<<dim3(NQKV_ / 32, C_ / 32), 256, 0, stream>>>(aw, awT, C_, NQKV_);
    transpose_cvt<<<dim3(C_ / 32, C_ / 32), 256, 0, stream>>>(pw, pwT, C_, C_);

    // 1) qkv = x @ c_attn_w + b   (bf16 out)
    gemm_bf16<<<dim3(NQKV_ / 128, M_ / 128), 256, 0, stream>>>(
        xb, awT, ab, qkvb, M_, NQKV_, C_, 1);

    // 2) flash attention (MFMA)
    attn_mfma<<<dim3(B_ * H_, T_ / 64), 256, 0, stream>>>(qkvb, yb);

    // 3) out = y @ c_proj_w + b   (fp32 out)
    gemm_bf16<<<dim3(C_ / 128, M_ / 128), 256, 0, stream>>>(
        yb, pwT, pb, out, M_, C_, C_, 0);
}

// Round 6
// 215.379 us; speedup vs baseline: 1.0509x; 1.0509x over previous
//
#include <hip/hip_runtime.h>

#define B_ 2
#define T_ 2048
#define C_ 1024
#define H_ 16
#define D_ 64
#define M_ (B_ * T_)       // 4096 rows
#define NQKV_ (3 * C_)     // 3072

typedef unsigned short us16;
typedef short bf16x8 __attribute__((ext_vector_type(8)));
typedef float f32x4 __attribute__((ext_vector_type(4)));

__device__ __forceinline__ f32x4 mfma16(bf16x8 a, bf16x8 b, f32x4 c) {
    return __builtin_amdgcn_mfma_f32_16x16x32_bf16(a, b, c, 0, 0, 0);
}

// float -> bf16 with round-to-nearest-even
__device__ __forceinline__ us16 f2bf(float f) {
    union { float f; unsigned int u; } v; v.f = f;
    unsigned int r = v.u + 0x7fffu + ((v.u >> 16) & 1u);
    return (us16)(r >> 16);
}

// two floats -> packed bf16 pair (single VALU op)
__device__ __forceinline__ unsigned int cvt_pk_bf16(float lo, float hi) {
    unsigned int r;
    asm("v_cvt_pk_bf16_f32 %0, %1, %2" : "=v"(r) : "v"(lo), "v"(hi));
    return r;
}

// async global->LDS, 16 B per lane; ldst must be wave-uniform (HW adds lane*16)
__device__ __forceinline__ void gl_lds16(const us16* g, us16* l) {
    __builtin_amdgcn_global_load_lds(
        (const __attribute__((address_space(1))) void*)g,
        (__attribute__((address_space(3))) void*)l,
        16, 0, 0);
}

// ---------------------------------------------------------------------------
// fp32 -> bf16 convert (8 elems/thread)
// ---------------------------------------------------------------------------
__global__ __launch_bounds__(256) void cvt_bf16(
    const float* __restrict__ in, us16* __restrict__ out, int n8)
{
    const int i = blockIdx.x * blockDim.x + threadIdx.x;
    if (i >= n8) return;
    const float4 a = ((const float4*)in)[2 * i];
    const float4 b = ((const float4*)in)[2 * i + 1];
    ushort4 lo = { f2bf(a.x), f2bf(a.y), f2bf(a.z), f2bf(a.w) };
    ushort4 hi = { f2bf(b.x), f2bf(b.y), f2bf(b.z), f2bf(b.w) };
    ((ushort4*)out)[2 * i] = lo;
    ((ushort4*)out)[2 * i + 1] = hi;
}

// ---------------------------------------------------------------------------
// W [K][N] fp32  ->  Wt [N][K] bf16   (32x32 LDS tiles)
// ---------------------------------------------------------------------------
__global__ __launch_bounds__(256) void transpose_cvt(
    const float* __restrict__ W, us16* __restrict__ Wt, int K, int N)
{
    __shared__ float tile[32][33];
    const int n0 = blockIdx.x * 32, k0 = blockIdx.y * 32;
    const int t = threadIdx.x;
    {
        const int k = t >> 3, n4 = (t & 7) * 4;
        const float4 v = *(const float4*)(W + (size_t)(k0 + k) * N + n0 + n4);
        tile[k][n4 + 0] = v.x; tile[k][n4 + 1] = v.y;
        tile[k][n4 + 2] = v.z; tile[k][n4 + 3] = v.w;
    }
    __syncthreads();
    {
        const int n = t >> 3, k4 = (t & 7) * 4;
        ushort4 o = { f2bf(tile[k4 + 0][n]), f2bf(tile[k4 + 1][n]),
                      f2bf(tile[k4 + 2][n]), f2bf(tile[k4 + 3][n]) };
        *(ushort4*)(Wt + (size_t)(n0 + n) * K + k0 + k4) = o;
    }
}

// ---------------------------------------------------------------------------
// bf16 MFMA GEMM: C[M][N] = A[M][K] @ Bt[N][K]^T + bias
// 128x128 block tile, BK=64, 4 waves each computing 64x64 (4x4 MFMA tiles).
// Staging via global_load_lds width=16 (async, correctness proven in R4) +
// T2-style XOR swizzle (m201/m231 both-sides pattern):
//   - LDS dest stays LINEAR (HW requirement: wave-uniform base + lane*16B)
//   - global SOURCE pre-swizzled: lane l stages granule (l&7)^(l>>3) of its
//     row, so LDS(row,g) holds global(row, g^(row&7))
//   - fragment READ applies the same XOR: granule G -> G^(row&7)=G^(cq&7)
// Bank math: read banks 4*(G^(cq&7)) distinct over cq=0..7 -> 32 banks
// covered, 2 lanes/bank = free (m136). Fixes R4's 16-way conflict regression.
// out_bf16: write bf16 via LDS-packed coalesced stores, else fp32 scalar.
// ---------------------------------------------------------------------------
__global__ __launch_bounds__(256) void gemm_bf16(
    const us16* __restrict__ A, const us16* __restrict__ Bt,
    const float* __restrict__ bias, void* __restrict__ Cout,
    int M, int N, int K, int out_bf16)
{
    // staging needs 2*128*64 = 16384 elems; epilogue Cs needs 128*136 = 17408
    __shared__ __align__(16) us16 smem[128 * 136];
    us16* sA = smem;                  // [128][64] linear, content XOR-swizzled
    us16* sB = smem + 128 * 64;       // [128][64] linear, content XOR-swizzled

    const int tid = threadIdx.x;
    const int lane = tid & 63, wave = tid >> 6;
    const int wr = wave >> 1, wc = wave & 1;
    const int cq = lane & 15, quad = lane >> 4;
    const int m0 = blockIdx.y * 128, n0 = blockIdx.x * 128;

    const int srow  = lane >> 3;                 // row within 8-row wave chunk
    const int sgran = (lane & 7) ^ srow;         // XOR-swizzled source granule
    const int scol  = sgran * 8;                 // elem offset of that granule

    f32x4 acc[4][4];
    #pragma unroll
    for (int i = 0; i < 4; ++i)
        #pragma unroll
        for (int j = 0; j < 4; ++j)
            acc[i][j] = (f32x4){0.f, 0.f, 0.f, 0.f};

    for (int k0 = 0; k0 < K; k0 += 64) {
        // ---- async stage: 4 chunks x (A,B); dest wave-uniform, src per-lane
        #pragma unroll
        for (int p = 0; p < 4; ++p) {
            const int r = p * 32 + wave * 8;     // wave-chunk base row (mult of 8)
            gl_lds16(A  + (size_t)(m0 + r + srow) * K + k0 + scol, sA + r * 64);
            gl_lds16(Bt + (size_t)(n0 + r + srow) * K + k0 + scol, sB + r * 64);
        }
        __syncthreads();   // drains vmcnt -> tiles resident

        #pragma unroll
        for (int kk = 0; kk < 64; kk += 32) {
            // granule of this k-step = (kk>>3)+quad; swizzle with row&7 = cq&7
            const int koS = (((kk >> 3) + quad) ^ (cq & 7)) << 3;
            bf16x8 af[4], bfg[4];
            #pragma unroll
            for (int i = 0; i < 4; ++i) {
                af[i]  = *(const bf16x8*)(sA + (wr * 64 + i * 16 + cq) * 64 + koS);
                bfg[i] = *(const bf16x8*)(sB + (wc * 64 + i * 16 + cq) * 64 + koS);
            }
            #pragma unroll
            for (int mi = 0; mi < 4; ++mi)
                #pragma unroll
                for (int ni = 0; ni < 4; ++ni)
                    acc[mi][ni] = mfma16(af[mi], bfg[ni], acc[mi][ni]);
        }
        __syncthreads();
    }

    // ---- epilogue ----
    if (out_bf16) {
        us16* Cs = smem;   // 128 x 136 (pad keeps 16B row alignment)
        #pragma unroll
        for (int mi = 0; mi < 4; ++mi)
            #pragma unroll
            for (int ni = 0; ni < 4; ++ni) {
                const int n = n0 + wc * 64 + ni * 16 + cq;
                const float bv = bias[n];
                #pragma unroll
                for (int r = 0; r < 4; ++r)
                    Cs[(wr * 64 + mi * 16 + quad * 4 + r) * 136 +
                       wc * 64 + ni * 16 + cq] = f2bf(acc[mi][ni][r] + bv);
            }
        __syncthreads();
        us16* Co = (us16*)Cout;
        #pragma unroll
        for (int p = 0; p < 8; ++p) {
            const int chunk = p * 256 + tid;
            const int r = chunk >> 4, c = (chunk & 15) * 8;
            *(uint4*)(Co + (size_t)(m0 + r) * N + n0 + c) =
                *(const uint4*)(Cs + r * 136 + c);
        }
    } else {
        float* Co = (float*)Cout;
        #pragma unroll
        for (int mi = 0; mi < 4; ++mi)
            #pragma unroll
            for (int ni = 0; ni < 4; ++ni) {
                const int n = n0 + wc * 64 + ni * 16 + cq;
                const float bv = bias[n];
                #pragma unroll
                for (int r = 0; r < 4; ++r)
                    Co[(size_t)(m0 + wr * 64 + mi * 16 + quad * 4 + r) * N + n] =
                        acc[mi][ni][r] + bv;
            }
    }
}

// ---------------------------------------------------------------------------
// MFMA flash attention (bf16 inputs, fp32 accum, causal).
// FROZEN at the R1/R4 known-good bytes. Three rounds (R2/R3/R5) showed that
// adding {s_setprio, __builtin_amdgcn_exp2f} to this inner loop corrupts
// results on this toolchain (bisect table in journal) despite being
// "provably" neutral — do NOT touch this kernel's inner-loop scheduling.
// ---------------------------------------------------------------------------
__global__ __launch_bounds__(256) void attn_mfma(
    const us16* __restrict__ qkv, us16* __restrict__ y)
{
    __shared__ __align__(16) us16 Ks[64][72];   // K tile, [t][d]
    __shared__ __align__(16) us16 Vt[64][72];   // V^T tile, [d][t]
    __shared__ __align__(16) us16 Ps[64][72];   // P, [q][t] (wave-private rows)

    const int tid = threadIdx.x;
    const int lane = tid & 63, wave = tid >> 6;
    const int cq = lane & 15, quad = lane >> 4;
    const int bh = blockIdx.x;
    const int qt = (int)gridDim.y - 1 - (int)blockIdx.y;   // heaviest first
    const int b = bh >> 4, h = bh & 15;

    const us16* base = qkv + (size_t)b * T_ * NQKV_ + h * D_;

    // Q fragments (A operand) straight from global; rows qt*64 + wave*16 + cq
    bf16x8 qf[2];
    {
        const us16* qrow = base + (size_t)(qt * 64 + wave * 16 + cq) * NQKV_;
        qf[0] = *(const bf16x8*)(qrow + quad * 8);
        qf[1] = *(const bf16x8*)(qrow + 32 + quad * 8);
    }

    // O^T accumulators: ot[dt][r] = O[d = dt*16+quad*4+r][q = wave*16+cq]
    f32x4 ot[4];
    #pragma unroll
    for (int j = 0; j < 4; ++j) ot[j] = (f32x4){0.f, 0.f, 0.f, 0.f};
    // row-sum accumulator: os[r] = sum_k P[q = wave*16+cq][k]  (all r equal)
    f32x4 os = (f32x4){0.f, 0.f, 0.f, 0.f};

    const bf16x8 onesf = (bf16x8){16256, 16256, 16256, 16256,
                                  16256, 16256, 16256, 16256}; // bf16 1.0 x8

    const float SCL = 0.125f * 1.44269504089f;   // fold 1/sqrt(D) and log2(e)
    const float SH  = -3.0f * 1.44269504089f;    // fixed shift (scores < 3)

    const int t2 = tid & 31, dc = tid >> 5;

    for (int kt = 0; kt <= qt; ++kt) {
        __syncthreads();   // previous iteration's MFMA reads complete
        // ---- stage K [t][d] ----
        #pragma unroll
        for (int p = 0; p < 2; ++p) {
            const int chunk = p * 256 + tid;
            const int r = chunk >> 3, c8 = (chunk & 7) * 8;
            const uint4 v = *(const uint4*)(base + (size_t)(kt * 64 + r) * NQKV_ + C_ + c8);
            *(uint4*)(&Ks[r][c8]) = v;
        }
        // ---- stage V transposed: Vt[d][t], packed pair writes ----
        {
            const us16* vp = base + (size_t)(kt * 64 + 2 * t2) * NQKV_ + 2 * C_ + dc * 8;
            const uint4 u0 = *(const uint4*)vp;
            const uint4 u1 = *(const uint4*)(vp + NQKV_);
            const us16* p0 = (const us16*)&u0;
            const us16* p1 = (const us16*)&u1;
            #pragma unroll
            for (int j = 0; j < 8; ++j) {
                const unsigned int packed =
                    (unsigned int)p0[j] | ((unsigned int)p1[j] << 16);
                *(unsigned int*)(&Vt[dc * 8 + j][2 * t2]) = packed;
            }
        }
        __syncthreads();

        // ---- S = Q K^T : 4 col tiles x (K=64 -> 2 mfma) ----
        f32x4 s[4];
        #pragma unroll
        for (int j = 0; j < 4; ++j) {
            const bf16x8 kf0 = *(const bf16x8*)(&Ks[j * 16 + cq][quad * 8]);
            const bf16x8 kf1 = *(const bf16x8*)(&Ks[j * 16 + cq][32 + quad * 8]);
            f32x4 t = (f32x4){0.f, 0.f, 0.f, 0.f};
            t = mfma16(qf[0], kf0, t);
            t = mfma16(qf[1], kf1, t);
            s[j] = t;
        }

        // ---- P = exp2(s*SCL + SH), causal mask on the diagonal tile ----
        float p[4][4];
        if (kt == qt) {
            const int qloc = wave * 16 + quad * 4;
            #pragma unroll
            for (int j = 0; j < 4; ++j) {
                const int kloc = j * 16 + cq;
                #pragma unroll
                for (int r = 0; r < 4; ++r) {
                    const float e = exp2f(fmaf(s[j][r], SCL, SH));
                    p[j][r] = (kloc > qloc + r) ? 0.f : e;
                }
            }
        } else {
            #pragma unroll
            for (int j = 0; j < 4; ++j)
                #pragma unroll
                for (int r = 0; r < 4; ++r)
                    p[j][r] = exp2f(fmaf(s[j][r], SCL, SH));
        }

        // ---- P -> LDS (wave-private rows; packed bf16 converts) ----
        #pragma unroll
        for (int j = 0; j < 4; ++j) {
            const unsigned int pk01 = cvt_pk_bf16(p[j][0], p[j][1]);
            const unsigned int pk23 = cvt_pk_bf16(p[j][2], p[j][3]);
            us16* pp = &Ps[wave * 16 + quad * 4][j * 16 + cq];
            pp[0]       = (us16)pk01;
            pp[72]      = (us16)(pk01 >> 16);
            pp[2 * 72]  = (us16)pk23;
            pp[3 * 72]  = (us16)(pk23 >> 16);
        }

        // ---- read P fragments back ----
        const bf16x8 pf0 = *(const bf16x8*)(&Ps[wave * 16 + cq][quad * 8]);
        const bf16x8 pf1 = *(const bf16x8*)(&Ps[wave * 16 + cq][32 + quad * 8]);

        // ---- O^T += V^T @ P^T ; row sums via ones-MFMA ----
        os = mfma16(onesf, pf0, os);
        os = mfma16(onesf, pf1, os);
        #pragma unroll
        for (int dt = 0; dt < 4; ++dt) {
            const bf16x8 vf0 = *(const bf16x8*)(&Vt[dt * 16 + cq][quad * 8]);
            const bf16x8 vf1 = *(const bf16x8*)(&Vt[dt * 16 + cq][32 + quad * 8]);
            ot[dt] = mfma16(vf0, pf0, ot[dt]);
            ot[dt] = mfma16(vf1, pf1, ot[dt]);
        }
    }

    // ---- epilogue: normalize, packed bf16 stores ----
    const float inv = 1.0f / os[0];
    const int row = qt * 64 + wave * 16 + cq;
    us16* yp = y + (size_t)(b * T_ + row) * C_ + h * D_ + quad * 4;
    #pragma unroll
    for (int dt = 0; dt < 4; ++dt) {
        ushort4 ov = { f2bf(ot[dt][0] * inv), f2bf(ot[dt][1] * inv),
                       f2bf(ot[dt][2] * inv), f2bf(ot[dt][3] * inv) };
        *(ushort4*)(yp + dt * 16) = ov;
    }
}

// ---------------------------------------------------------------------------
extern "C" void kernel_launch(void* const* d_in, const int* in_sizes, int n_in,
                              void* d_out, int out_size, void* d_ws, size_t ws_size,
                              hipStream_t stream)
{
    const float* x  = (const float*)d_in[0];   // [B,T,C]
    const float* aw = (const float*)d_in[1];   // [C,3C]
    const float* ab = (const float*)d_in[2];   // [3C]
    const float* pw = (const float*)d_in[3];   // [C,C]
    const float* pb = (const float*)d_in[4];   // [C]
    float* out = (float*)d_out;                // [B,T,C] fp32

    us16* xb   = (us16*)d_ws;                        // [4096][1024]
    us16* awT  = xb  + (size_t)M_ * C_;              // [3072][1024]
    us16* pwT  = awT + (size_t)NQKV_ * C_;           // [1024][1024]
    us16* qkvb = pwT + (size_t)C_ * C_;              // [4096][3072]
    us16* yb   = qkvb + (size_t)M_ * NQKV_;          // [4096][1024]

    // pre-pass: bf16 conversions
    cvt_bf16<<<(M_ * C_ / 8 + 255) / 256, 256, 0, stream>>>(x, xb, M_ * C_ / 8);
    transpose_cvt<<<dim3(NQKV_ / 32, C_ / 32), 256, 0, stream>>>(aw, awT, C_, NQKV_);
    transpose_cvt<<<dim3(C_ / 32, C_ / 32), 256, 0, stream>>>(pw, pwT, C_, C_);

    // 1) qkv = x @ c_attn_w + b   (bf16 out)
    gemm_bf16<<<dim3(NQKV_ / 128, M_ / 128), 256, 0, stream>>>(
        xb, awT, ab, qkvb, M_, NQKV_, C_, 1);

    // 2) flash attention (MFMA)
    attn_mfma<<<dim3(B_ * H_, T_ / 64), 256, 0, stream>>>(qkvb, yb);

    // 3) out = y @ c_proj_w + b   (fp32 out)
    gemm_bf16<<<dim3(C_ / 128, M_ / 128), 256, 0, stream>>>(
        yb, pwT, pb, out, M_, C_, C_, 0);
}